// Round 1
// baseline (1736.543 us; speedup 1.0000x reference)
//
#include <hip/hip_runtime.h>
#include <hip/hip_bf16.h>

#define T_TOK 2048
#define HID 2048
#define MINTER 1024
#define SINTER 4096
#define NEXP 16

typedef unsigned short u16;
typedef short short8 __attribute__((ext_vector_type(8)));
typedef float f32x4 __attribute__((ext_vector_type(4)));

__device__ __forceinline__ u16 f2bf(float f) {
    union { float f; unsigned u; } v; v.f = f;
    unsigned u = v.u;
    unsigned r = (u + 0x7FFFu + ((u >> 16) & 1u)) >> 16;
    return (u16)r;
}

// ---------------- x fp32 -> bf16 ----------------
__global__ __launch_bounds__(256) void cvt_kernel(const float* __restrict__ in,
                                                  u16* __restrict__ out, int n4) {
    int i = blockIdx.x * 256 + threadIdx.x;
    if (i >= n4) return;
    float4 v = ((const float4*)in)[i];
    ushort4 o;
    o.x = f2bf(v.x); o.y = f2bf(v.y); o.z = f2bf(v.z); o.w = f2bf(v.w);
    ((ushort4*)out)[i] = o;
}

// ---------------- router: logits -> sigmoid -> group top-k -> scatter ----------------
__global__ __launch_bounds__(256) void router_kernel(
    const float* __restrict__ x, const float* __restrict__ rw, const float* __restrict__ ebias,
    int* __restrict__ counts, int* __restrict__ bid, float* __restrict__ bw)
{
    int t = blockIdx.x;
    int tid = threadIdx.x;
    int e = tid >> 4, j = tid & 15;
    const float* xp = x + (size_t)t * HID;
    const float* wp = rw + (size_t)e * HID;
    float sum = 0.f;
    #pragma unroll 4
    for (int h = j; h < HID; h += 16) sum += xp[h] * wp[h];
    sum += __shfl_xor(sum, 8);
    sum += __shfl_xor(sum, 4);
    sum += __shfl_xor(sum, 2);
    sum += __shfl_xor(sum, 1);
    __shared__ float sc[NEXP];
    if (j == 0) sc[e] = 1.f / (1.f + expf(-sum));
    __syncthreads();
    if (tid == 0) {
        float s[NEXP];
        #pragma unroll
        for (int i = 0; i < NEXP; i++) s[i] = sc[i] + ebias[i];
        float gs[4];
        #pragma unroll
        for (int g = 0; g < 4; g++) {
            float a = s[4*g], b = s[4*g+1], c = s[4*g+2], d = s[4*g+3];
            float hi1 = fmaxf(a,b), lo1 = fminf(a,b);
            float hi2 = fmaxf(c,d), lo2 = fminf(c,d);
            float mx = fmaxf(hi1, hi2);
            float se = fmaxf(fminf(hi1, hi2), fmaxf(lo1, lo2));
            gs[g] = mx + se;
        }
        int g0 = 0;
        for (int g = 1; g < 4; g++) if (gs[g] > gs[g0]) g0 = g;
        int g1 = -1;
        for (int g = 0; g < 4; g++) { if (g == g0) continue; if (g1 < 0 || gs[g] > gs[g1]) g1 = g; }
        int e0 = -1, e1 = -1;
        for (int i = 0; i < NEXP; i++) {
            int g = i >> 2;
            if (g != g0 && g != g1) continue;
            if (e0 < 0 || s[i] > s[e0]) e0 = i;
        }
        for (int i = 0; i < NEXP; i++) {
            int g = i >> 2;
            if (g != g0 && g != g1) continue;
            if (i == e0) continue;
            if (e1 < 0 || s[i] > s[e1]) e1 = i;
        }
        float w0 = sc[e0], w1 = sc[e1];
        float inv = 1.f / (w0 + w1 + 1e-20f);
        w0 *= inv; w1 *= inv;
        int p0 = atomicAdd(&counts[e0], 1);
        bid[e0 * T_TOK + p0] = t * 2;
        bw [e0 * T_TOK + p0] = w0;
        int p1 = atomicAdd(&counts[e1], 1);
        bid[e1 * T_TOK + p1] = t * 2 + 1;
        bw [e1 * T_TOK + p1] = w1;
    }
}

// ---------------- 128x128 MFMA GEMM, A bf16 (optionally row-gathered), B fp32 cvt-on-stage ----
// EPI: 0 = fp32 store; 1 = relu^2 -> bf16 store; 2 = relu^2 * rowweight -> bf16 store
#define BM 128
#define BN 128
#define BKT 64
#define LSTR 72   // bf16 elems per LDS row; 144 B (16B aligned, conflict-benign)

template<int EPI, bool GATHER, int SHIFT>
__global__ __launch_bounds__(256, 2) void gemm_kernel(
    const u16* __restrict__ A, const float* __restrict__ B, void* __restrict__ Cout,
    int M, int N, int K, int ldA, int ldB, int ldC,
    const int* __restrict__ ids, const float* __restrict__ wv, const int* __restrict__ counts)
{
    if constexpr (GATHER) {
        int e = blockIdx.z;
        M = counts[e];
        B += (size_t)e * K * N;
        ids += e * T_TOK;
        wv  += e * T_TOK;
    }
    int m0 = blockIdx.x * BM;
    if constexpr (GATHER) { if (m0 >= M) return; }
    int n0 = blockIdx.y * BN;

    __shared__ alignas(16) u16 As[BM * LSTR];
    __shared__ alignas(16) u16 Bs[BN * LSTR];
    __shared__ int   idsL[BM];
    __shared__ float wL[BM];

    int tid = threadIdx.x;

    if constexpr (GATHER) {
        if (tid < BM) {
            int p = m0 + tid;
            if (p >= M) p = M - 1;
            idsL[tid] = ids[p];
            wL[tid] = (EPI == 2) ? wv[p] : 0.f;
        }
        __syncthreads();
    }

    // A staging assignment: 4 rows/thread, 8 bf16 (16B) per row-seg
    int arow = tid >> 3;           // 0..31
    int aseg = (tid & 7) * 8;      // 0..56
    const u16* aPtr[4];
    #pragma unroll
    for (int i = 0; i < 4; i++) {
        int r = arow + 32 * i;
        size_t grow;
        if constexpr (GATHER) grow = (size_t)(idsL[r] >> SHIFT);
        else grow = (size_t)(m0 + r);
        aPtr[i] = A + grow * (size_t)ldA + aseg;
    }

    // B staging assignment: k-pair rows, 4 n per thread-load
    int ns  = (tid & 31) * 4;
    int kp0 = tid >> 5;            // 0..7

    f32x4 acc[4][4] = {};

    int lane = tid & 63;
    int wid  = tid >> 6;
    int wm = (wid & 1) * 64;
    int wn = (wid >> 1) * 64;
    int lrow = lane & 15;
    int lq   = lane >> 4;

    unsigned* BsW = (unsigned*)Bs;

    for (int k0 = 0; k0 < K; k0 += BKT) {
        // ---- stage A (bf16, row-major, pad-72) ----
        #pragma unroll
        for (int i = 0; i < 4; i++) {
            uint4 v = *(const uint4*)(aPtr[i] + k0);
            *(uint4*)&As[(arow + 32*i) * LSTR + aseg] = v;
        }
        // ---- stage B transposed: Bs[n][k], fp32->bf16, chunk-XOR swizzle ----
        #pragma unroll
        for (int i = 0; i < 4; i++) {
            int kp   = kp0 + 8 * i;       // 0..31  (k = 2kp, 2kp+1)
            int krow = k0 + 2 * kp;
            const float* bp = B + (size_t)krow * ldB + n0 + ns;
            float4 b0 = *(const float4*)bp;
            float4 b1 = *(const float4*)(bp + ldB);
            unsigned pk[4];
            pk[0] = (unsigned)f2bf(b0.x) | ((unsigned)f2bf(b1.x) << 16);
            pk[1] = (unsigned)f2bf(b0.y) | ((unsigned)f2bf(b1.y) << 16);
            pk[2] = (unsigned)f2bf(b0.z) | ((unsigned)f2bf(b1.z) << 16);
            pk[3] = (unsigned)f2bf(b0.w) | ((unsigned)f2bf(b1.w) << 16);
            int c = kp >> 2, klo = kp & 3;
            #pragma unroll
            for (int jj = 0; jj < 4; jj++) {
                int n  = ns + jj;
                int cs = c ^ ((n >> 2) & 7);
                BsW[n * (LSTR/2) + cs * 4 + klo] = pk[jj];
            }
        }
        __syncthreads();
        // ---- MFMA over the 64-deep tile (two K=32 chunks) ----
        #pragma unroll
        for (int kc = 0; kc < BKT; kc += 32) {
            short8 af[4], bfr[4];
            #pragma unroll
            for (int im = 0; im < 4; im++) {
                int row = wm + im*16 + lrow;
                af[im] = *(const short8*)&As[row * LSTR + kc + lq * 8];
            }
            #pragma unroll
            for (int in = 0; in < 4; in++) {
                int n  = wn + in*16 + lrow;
                int c  = (kc >> 3) + lq;
                int cs = c ^ ((n >> 2) & 7);
                bfr[in] = *(const short8*)&Bs[n * LSTR + cs * 8];
            }
            #pragma unroll
            for (int im = 0; im < 4; im++)
                #pragma unroll
                for (int in = 0; in < 4; in++)
                    acc[im][in] = __builtin_amdgcn_mfma_f32_16x16x32_bf16(
                        af[im], bfr[in], acc[im][in], 0, 0, 0);
        }
        __syncthreads();
    }

    // ---- epilogue ----
    float* Cf = (float*)Cout;
    u16*   Ch = (u16*)Cout;
    #pragma unroll
    for (int im = 0; im < 4; im++) {
        #pragma unroll
        for (int in = 0; in < 4; in++) {
            int ncol = n0 + wn + in*16 + lrow;
            #pragma unroll
            for (int r = 0; r < 4; r++) {
                int mrow = wm + im*16 + lq*4 + r;
                int gm = m0 + mrow;
                size_t crow;
                if constexpr (GATHER) {
                    if (gm >= M) continue;
                    crow = (size_t)idsL[mrow];
                } else {
                    crow = (size_t)gm;
                }
                float v = acc[im][in][r];
                if constexpr (EPI == 0) {
                    Cf[crow * (size_t)ldC + ncol] = v;
                } else {
                    float rl = v > 0.f ? v * v : 0.f;
                    if constexpr (EPI == 2) rl *= wL[mrow];
                    Ch[crow * (size_t)ldC + ncol] = f2bf(rl);
                }
            }
        }
    }
}

// ---------------- out = shared + routed[2t] + routed[2t+1] ----------------
__global__ __launch_bounds__(256) void final_add_kernel(
    const float* __restrict__ sh, const float* __restrict__ ro,
    float* __restrict__ out, int n4)
{
    int i = blockIdx.x * 256 + threadIdx.x;
    if (i >= n4) return;
    int t  = i >> 9;        // 512 float4 per 2048-wide row
    int c4 = i & 511;
    float4 a = ((const float4*)sh)[i];
    float4 b = ((const float4*)ro)[(size_t)(2*t)     * 512 + c4];
    float4 c = ((const float4*)ro)[(size_t)(2*t + 1) * 512 + c4];
    float4 o;
    o.x = a.x + b.x + c.x;
    o.y = a.y + b.y + c.y;
    o.z = a.z + b.z + c.z;
    o.w = a.w + b.w + c.w;
    ((float4*)out)[i] = o;
}

extern "C" void kernel_launch(void* const* d_in, const int* in_sizes, int n_in,
                              void* d_out, int out_size, void* d_ws, size_t ws_size,
                              hipStream_t stream) {
    (void)in_sizes; (void)n_in; (void)out_size; (void)ws_size;
    const float* x  = (const float*)d_in[0];
    const float* rw = (const float*)d_in[1];
    const float* eb = (const float*)d_in[2];
    const float* wu = (const float*)d_in[3];
    const float* wd = (const float*)d_in[4];
    const float* su = (const float*)d_in[5];
    const float* sd = (const float*)d_in[6];
    float* out = (float*)d_out;

    char* p = (char*)d_ws;
    u16*  x_bf   = (u16*)p;   p += (size_t)T_TOK * HID * 2;          // 8.4 MB
    u16*  h_sh   = (u16*)p;   p += (size_t)T_TOK * SINTER * 2;       // 16.8 MB
    u16*  act    = (u16*)p;   p += (size_t)T_TOK * 2 * MINTER * 2;   // 8.4 MB
    float* sh_out = (float*)p; p += (size_t)T_TOK * HID * 4;         // 16.8 MB
    float* r_out  = (float*)p; p += (size_t)T_TOK * 2 * HID * 4;     // 33.6 MB
    int*   counts = (int*)p;   p += 256;
    int*   bid    = (int*)p;   p += (size_t)NEXP * T_TOK * 4;
    float* bw     = (float*)p; p += (size_t)NEXP * T_TOK * 4;

    hipMemsetAsync(counts, 0, NEXP * sizeof(int), stream);

    int n4 = T_TOK * HID / 4;
    cvt_kernel<<<(n4 + 255) / 256, 256, 0, stream>>>(x, x_bf, n4);

    router_kernel<<<T_TOK, 256, 0, stream>>>(x, rw, eb, counts, bid, bw);

    // shared up: [T,H]x[H,S] -> relu2 -> bf16 h_sh
    gemm_kernel<1, false, 0><<<dim3(T_TOK/128, SINTER/128, 1), 256, 0, stream>>>(
        x_bf, su, h_sh, T_TOK, SINTER, HID, HID, SINTER, SINTER, nullptr, nullptr, nullptr);

    // shared down: [T,S]x[S,H] -> fp32 sh_out
    gemm_kernel<0, false, 0><<<dim3(T_TOK/128, HID/128, 1), 256, 0, stream>>>(
        h_sh, sd, sh_out, T_TOK, HID, SINTER, SINTER, HID, HID, nullptr, nullptr, nullptr);

    // routed up (grouped, gather rows = token): relu2 * w -> bf16 act[tk]
    gemm_kernel<2, true, 1><<<dim3(T_TOK/128, MINTER/128, NEXP), 256, 0, stream>>>(
        x_bf, wu, act, 0, MINTER, HID, HID, MINTER, MINTER, bid, bw, counts);

    // routed down (grouped, gather rows = tk): fp32 r_out[tk]
    gemm_kernel<0, true, 0><<<dim3(T_TOK/128, HID/128, NEXP), 256, 0, stream>>>(
        act, wd, r_out, 0, HID, MINTER, MINTER, HID, HID, bid, bw, counts);

    final_add_kernel<<<(n4 + 255) / 256, 256, 0, stream>>>(sh_out, r_out, out, n4);
}

// Round 2
// 904.835 us; speedup vs baseline: 1.9192x; 1.9192x over previous
//
#include <hip/hip_runtime.h>
#include <hip/hip_bf16.h>

#define T_TOK 2048
#define HID 2048
#define MINTER 1024
#define SINTER 4096
#define NEXP 16

typedef unsigned short u16;
typedef unsigned int u32;
typedef short short8 __attribute__((ext_vector_type(8)));
typedef float f32x4 __attribute__((ext_vector_type(4)));

__device__ __forceinline__ u16 f2bf(float f) {
    union { float f; unsigned u; } v; v.f = f;
    unsigned u = v.u;
    unsigned r = (u + 0x7FFFu + ((u >> 16) & 1u)) >> 16;
    return (u16)r;
}

// async global->LDS, 16B per lane; LDS dest must be wave-uniform base (+lane*16)
__device__ __forceinline__ void gload16(const void* g, void* s) {
    __builtin_amdgcn_global_load_lds(
        (const __attribute__((address_space(1))) u32*)g,
        (__attribute__((address_space(3))) u32*)s, 16, 0, 0);
}

// ---------------- x fp32 -> bf16 ----------------
__global__ __launch_bounds__(256) void cvt_kernel(const float* __restrict__ in,
                                                  u16* __restrict__ out, int n4) {
    int i = blockIdx.x * 256 + threadIdx.x;
    if (i >= n4) return;
    float4 v = ((const float4*)in)[i];
    ushort4 o;
    o.x = f2bf(v.x); o.y = f2bf(v.y); o.z = f2bf(v.z); o.w = f2bf(v.w);
    ((ushort4*)out)[i] = o;
}

// ---------------- [Z][K][N] fp32 -> [Z][N][K] bf16 transpose ----------------
__global__ __launch_bounds__(256) void transpose_cvt_kernel(
    const float* __restrict__ in, u16* __restrict__ out, int K, int N)
{
    __shared__ float t[64][65];
    size_t zoff = (size_t)blockIdx.z * K * N;
    in += zoff; out += zoff;
    int k0 = blockIdx.x * 64, n0 = blockIdx.y * 64;
    int tid = threadIdx.x;
    int r = tid >> 4, c4 = (tid & 15) * 4;
    #pragma unroll
    for (int i = 0; i < 4; i++) {
        float4 v = *(const float4*)&in[(size_t)(k0 + r + 16*i) * N + n0 + c4];
        t[r + 16*i][c4]     = v.x;
        t[r + 16*i][c4 + 1] = v.y;
        t[r + 16*i][c4 + 2] = v.z;
        t[r + 16*i][c4 + 3] = v.w;
    }
    __syncthreads();
    #pragma unroll
    for (int i = 0; i < 4; i++) {
        int n = r + 16*i;
        ushort4 o;
        o.x = f2bf(t[c4 + 0][n]);
        o.y = f2bf(t[c4 + 1][n]);
        o.z = f2bf(t[c4 + 2][n]);
        o.w = f2bf(t[c4 + 3][n]);
        *(ushort4*)&out[(size_t)(n0 + n) * K + k0 + c4] = o;
    }
}

// ---------------- router: logits -> sigmoid -> group top-k -> scatter ----------------
__global__ __launch_bounds__(256) void router_kernel(
    const float* __restrict__ x, const float* __restrict__ rw, const float* __restrict__ ebias,
    int* __restrict__ counts, int* __restrict__ bid, float* __restrict__ bw)
{
    int t = blockIdx.x;
    int tid = threadIdx.x;
    int e = tid >> 4, j = tid & 15;
    const float* xp = x + (size_t)t * HID;
    const float* wp = rw + (size_t)e * HID;
    float sum = 0.f;
    #pragma unroll 4
    for (int h = j; h < HID; h += 16) sum += xp[h] * wp[h];
    sum += __shfl_xor(sum, 8);
    sum += __shfl_xor(sum, 4);
    sum += __shfl_xor(sum, 2);
    sum += __shfl_xor(sum, 1);
    __shared__ float sc[NEXP];
    if (j == 0) sc[e] = 1.f / (1.f + expf(-sum));
    __syncthreads();
    if (tid == 0) {
        float s[NEXP];
        #pragma unroll
        for (int i = 0; i < NEXP; i++) s[i] = sc[i] + ebias[i];
        float gs[4];
        #pragma unroll
        for (int g = 0; g < 4; g++) {
            float a = s[4*g], b = s[4*g+1], c = s[4*g+2], d = s[4*g+3];
            float hi1 = fmaxf(a,b), lo1 = fminf(a,b);
            float hi2 = fmaxf(c,d), lo2 = fminf(c,d);
            float mx = fmaxf(hi1, hi2);
            float se = fmaxf(fminf(hi1, hi2), fmaxf(lo1, lo2));
            gs[g] = mx + se;
        }
        int g0 = 0;
        for (int g = 1; g < 4; g++) if (gs[g] > gs[g0]) g0 = g;
        int g1 = -1;
        for (int g = 0; g < 4; g++) { if (g == g0) continue; if (g1 < 0 || gs[g] > gs[g1]) g1 = g; }
        int e0 = -1, e1 = -1;
        for (int i = 0; i < NEXP; i++) {
            int g = i >> 2;
            if (g != g0 && g != g1) continue;
            if (e0 < 0 || s[i] > s[e0]) e0 = i;
        }
        for (int i = 0; i < NEXP; i++) {
            int g = i >> 2;
            if (g != g0 && g != g1) continue;
            if (i == e0) continue;
            if (e1 < 0 || s[i] > s[e1]) e1 = i;
        }
        float w0 = sc[e0], w1 = sc[e1];
        float inv = 1.f / (w0 + w1 + 1e-20f);
        w0 *= inv; w1 *= inv;
        int p0 = atomicAdd(&counts[e0], 1);
        bid[e0 * T_TOK + p0] = t * 2;
        bw [e0 * T_TOK + p0] = w0;
        int p1 = atomicAdd(&counts[e1], 1);
        bid[e1 * T_TOK + p1] = t * 2 + 1;
        bw [e1 * T_TOK + p1] = w1;
    }
}

// =================== fused UP dispatch ===================
// blocks [0,512):   shared-up  : hsh[T,S]   = relu2(xbf @ suT^T)       (bf16)
// blocks [512,...): routed-up  : act[tk,I]  = relu2(xbf[t] @ wuT^T)*w  (bf16)
// Both K = HID. m97-style: global_load_lds staging, 128x128 tile, BK=64.
__global__ __launch_bounds__(256, 3) void up_kernel(
    const u16* __restrict__ xbf, const u16* __restrict__ suT,
    const u16* __restrict__ wuT, u16* __restrict__ hsh, u16* __restrict__ act,
    const int* __restrict__ counts, const int* __restrict__ bid,
    const float* __restrict__ bw)
{
    __shared__ alignas(16) u16 As[128 * 64];
    __shared__ alignas(16) u16 Bs[128 * 64];
    __shared__ int   idsL[128];
    __shared__ float wL[128];

    int b = blockIdx.x;
    int tid = threadIdx.x;
    bool routed = (b >= 512);
    int e = 0, mblk, nblk, M = T_TOK;
    const u16* BT;
    if (!routed) { mblk = b & 15; nblk = b >> 4; BT = suT; }
    else {
        int rb = b - 512; e = rb >> 7; int rem = rb & 127;
        mblk = rem & 15; nblk = rem >> 4;
        M = counts[e];
        if (mblk * 128 >= M) return;
        BT = wuT + (size_t)e * MINTER * HID;
    }
    int m0 = mblk * 128, n0 = nblk * 128;

    if (routed) {
        if (tid < 128) {
            int p = m0 + tid; if (p >= M) p = M - 1;
            idsL[tid] = bid[e * T_TOK + p];
            wL[tid]   = bw [e * T_TOK + p];
        }
        __syncthreads();
    }

    int lane = tid & 63, wid = tid >> 6;
    int rsub = lane >> 3, kseg = (lane & 7) * 8;

    const u16* aG[4]; const u16* bG[4];
    #pragma unroll
    for (int i = 0; i < 4; i++) {
        int rr = wid * 32 + i * 8 + rsub;
        size_t ar = routed ? (size_t)(idsL[rr] >> 1) : (size_t)(m0 + rr);
        aG[i] = xbf + ar * HID + kseg;
        bG[i] = BT + (size_t)(n0 + rr) * HID + kseg;
    }

    f32x4 acc[4][4] = {};
    int wm = (wid & 1) * 64, wn = (wid >> 1) * 64;
    int lrow = lane & 15, lq = lane >> 4;

    for (int k0 = 0; k0 < HID; k0 += 64) {
        #pragma unroll
        for (int i = 0; i < 4; i++) {
            gload16(aG[i] + k0, &As[(wid * 32 + i * 8) * 64]);
            gload16(bG[i] + k0, &Bs[(wid * 32 + i * 8) * 64]);
        }
        __syncthreads();
        #pragma unroll
        for (int kc = 0; kc < 64; kc += 32) {
            short8 af[4], bf2[4];
            #pragma unroll
            for (int im = 0; im < 4; im++)
                af[im] = *(const short8*)&As[(wm + im*16 + lrow) * 64 + kc + lq * 8];
            #pragma unroll
            for (int in = 0; in < 4; in++)
                bf2[in] = *(const short8*)&Bs[(wn + in*16 + lrow) * 64 + kc + lq * 8];
            #pragma unroll
            for (int im = 0; im < 4; im++)
                #pragma unroll
                for (int in = 0; in < 4; in++)
                    acc[im][in] = __builtin_amdgcn_mfma_f32_16x16x32_bf16(
                        af[im], bf2[in], acc[im][in], 0, 0, 0);
        }
        __syncthreads();
    }

    #pragma unroll
    for (int im = 0; im < 4; im++) {
        #pragma unroll
        for (int in = 0; in < 4; in++) {
            int ncol = n0 + wn + in*16 + lrow;
            #pragma unroll
            for (int r = 0; r < 4; r++) {
                int mrow = wm + im*16 + lq*4 + r;
                float v = acc[im][in][r];
                float rl = v > 0.f ? v * v : 0.f;
                if (!routed) {
                    hsh[(size_t)(m0 + mrow) * SINTER + ncol] = f2bf(rl);
                } else {
                    if (m0 + mrow < M) {
                        int tk = idsL[mrow];
                        act[(size_t)tk * MINTER + ncol] = f2bf(rl * wL[mrow]);
                    }
                }
            }
        }
    }
}

// =================== fused DOWN dispatch ===================
// blocks [0,256):   shared-down: sh_out[T,H] = hsh @ sdT^T   (fp32), K=S
// blocks [256,...): routed-down: r_out[tk,H] = act[tk] @ wdT^T (fp32), K=I
__global__ __launch_bounds__(256, 3) void down_kernel(
    const u16* __restrict__ hsh, const u16* __restrict__ sdT,
    const u16* __restrict__ act, const u16* __restrict__ wdT,
    float* __restrict__ sh_out, float* __restrict__ r_out,
    const int* __restrict__ counts, const int* __restrict__ bid)
{
    __shared__ alignas(16) u16 As[128 * 64];
    __shared__ alignas(16) u16 Bs[128 * 64];
    __shared__ int idsL[128];

    int b = blockIdx.x;
    int tid = threadIdx.x;
    bool routed = (b >= 256);
    int e = 0, mblk, nblk, M = T_TOK, K, ldA;
    const u16* A; const u16* BT; float* C;
    if (!routed) {
        mblk = b & 15; nblk = b >> 4;
        A = hsh; ldA = SINTER; K = SINTER; BT = sdT; C = sh_out;
    } else {
        int rb = b - 256; e = rb >> 8; int rem = rb & 255;
        mblk = rem & 15; nblk = rem >> 4;
        M = counts[e];
        if (mblk * 128 >= M) return;
        A = act; ldA = MINTER; K = MINTER;
        BT = wdT + (size_t)e * HID * MINTER;
        C = r_out;
    }
    int m0 = mblk * 128, n0 = nblk * 128;

    if (routed) {
        if (tid < 128) {
            int p = m0 + tid; if (p >= M) p = M - 1;
            idsL[tid] = bid[e * T_TOK + p];
        }
        __syncthreads();
    }

    int lane = tid & 63, wid = tid >> 6;
    int rsub = lane >> 3, kseg = (lane & 7) * 8;

    const u16* aG[4]; const u16* bG[4];
    #pragma unroll
    for (int i = 0; i < 4; i++) {
        int rr = wid * 32 + i * 8 + rsub;
        size_t ar = routed ? (size_t)idsL[rr] : (size_t)(m0 + rr);
        aG[i] = A + ar * (size_t)ldA + kseg;
        bG[i] = BT + (size_t)(n0 + rr) * K + kseg;
    }

    f32x4 acc[4][4] = {};
    int wm = (wid & 1) * 64, wn = (wid >> 1) * 64;
    int lrow = lane & 15, lq = lane >> 4;

    for (int k0 = 0; k0 < K; k0 += 64) {
        #pragma unroll
        for (int i = 0; i < 4; i++) {
            gload16(aG[i] + k0, &As[(wid * 32 + i * 8) * 64]);
            gload16(bG[i] + k0, &Bs[(wid * 32 + i * 8) * 64]);
        }
        __syncthreads();
        #pragma unroll
        for (int kc = 0; kc < 64; kc += 32) {
            short8 af[4], bf2[4];
            #pragma unroll
            for (int im = 0; im < 4; im++)
                af[im] = *(const short8*)&As[(wm + im*16 + lrow) * 64 + kc + lq * 8];
            #pragma unroll
            for (int in = 0; in < 4; in++)
                bf2[in] = *(const short8*)&Bs[(wn + in*16 + lrow) * 64 + kc + lq * 8];
            #pragma unroll
            for (int im = 0; im < 4; im++)
                #pragma unroll
                for (int in = 0; in < 4; in++)
                    acc[im][in] = __builtin_amdgcn_mfma_f32_16x16x32_bf16(
                        af[im], bf2[in], acc[im][in], 0, 0, 0);
        }
        __syncthreads();
    }

    #pragma unroll
    for (int im = 0; im < 4; im++) {
        #pragma unroll
        for (int in = 0; in < 4; in++) {
            int ncol = n0 + wn + in*16 + lrow;
            #pragma unroll
            for (int r = 0; r < 4; r++) {
                int mrow = wm + im*16 + lq*4 + r;
                float v = acc[im][in][r];
                if (!routed) {
                    C[(size_t)(m0 + mrow) * HID + ncol] = v;
                } else {
                    if (m0 + mrow < M) {
                        int tk = idsL[mrow];
                        C[(size_t)tk * HID + ncol] = v;
                    }
                }
            }
        }
    }
}

// ---------------- out = shared + routed[2t] + routed[2t+1] ----------------
__global__ __launch_bounds__(256) void final_add_kernel(
    const float* __restrict__ sh, const float* __restrict__ ro,
    float* __restrict__ out, int n4)
{
    int i = blockIdx.x * 256 + threadIdx.x;
    if (i >= n4) return;
    int t  = i >> 9;
    int c4 = i & 511;
    float4 a = ((const float4*)sh)[i];
    float4 b = ((const float4*)ro)[(size_t)(2*t)     * 512 + c4];
    float4 c = ((const float4*)ro)[(size_t)(2*t + 1) * 512 + c4];
    float4 o;
    o.x = a.x + b.x + c.x;
    o.y = a.y + b.y + c.y;
    o.z = a.z + b.z + c.z;
    o.w = a.w + b.w + c.w;
    ((float4*)out)[i] = o;
}

extern "C" void kernel_launch(void* const* d_in, const int* in_sizes, int n_in,
                              void* d_out, int out_size, void* d_ws, size_t ws_size,
                              hipStream_t stream) {
    (void)in_sizes; (void)n_in; (void)out_size; (void)ws_size;
    const float* x  = (const float*)d_in[0];
    const float* rw = (const float*)d_in[1];
    const float* eb = (const float*)d_in[2];
    const float* wu = (const float*)d_in[3];
    const float* wd = (const float*)d_in[4];
    const float* su = (const float*)d_in[5];
    const float* sd = (const float*)d_in[6];
    float* out = (float*)d_out;

    char* p = (char*)d_ws;
    u16*  x_bf = (u16*)p;  p += (size_t)T_TOK * HID * 2;            // 8.4 MB
    u16*  suT  = (u16*)p;  p += (size_t)SINTER * HID * 2;           // 16.8 MB
    u16*  sdT  = (u16*)p;  p += (size_t)HID * SINTER * 2;           // 16.8 MB
    u16*  wuT  = (u16*)p;  p += (size_t)NEXP * MINTER * HID * 2;    // 67.1 MB
    u16*  wdT  = (u16*)p;  p += (size_t)NEXP * HID * MINTER * 2;    // 67.1 MB
    u16*  hsh  = (u16*)p;  p += (size_t)T_TOK * SINTER * 2;         // 16.8 MB
    u16*  act  = (u16*)p;  p += (size_t)T_TOK * 2 * MINTER * 2;     // 8.4 MB
    int*   counts = (int*)p; p += 256;
    int*   bid    = (int*)p; p += (size_t)NEXP * T_TOK * 4;
    float* bw     = (float*)p; p += (size_t)NEXP * T_TOK * 4;
    // aliased (lifetimes disjoint, stream-ordered):
    float* sh_out = (float*)x_bf;   // 16.8 MB over x_bf+suT (dead after up)
    float* r_out  = (float*)wuT;    // 33.6 MB over wuT (dead after up)

    hipMemsetAsync(counts, 0, NEXP * sizeof(int), stream);

    int n4 = T_TOK * HID / 4;
    cvt_kernel<<<(n4 + 255) / 256, 256, 0, stream>>>(x, x_bf, n4);

    // weight convert+transpose to bf16 B^T layouts
    transpose_cvt_kernel<<<dim3(2048/64, 4096/64, 1),  256, 0, stream>>>(su, suT, 2048, 4096);
    transpose_cvt_kernel<<<dim3(4096/64, 2048/64, 1),  256, 0, stream>>>(sd, sdT, 4096, 2048);
    transpose_cvt_kernel<<<dim3(2048/64, 1024/64, 16), 256, 0, stream>>>(wu, wuT, 2048, 1024);
    transpose_cvt_kernel<<<dim3(1024/64, 2048/64, 16), 256, 0, stream>>>(wd, wdT, 1024, 2048);

    router_kernel<<<T_TOK, 256, 0, stream>>>(x, rw, eb, counts, bid, bw);

    // fused up: 512 shared tiles + 16e*8n*16m routed tiles
    up_kernel<<<512 + NEXP * 8 * 16, 256, 0, stream>>>(
        x_bf, suT, wuT, hsh, act, counts, bid, bw);

    // fused down: 256 shared tiles + 16e*16n*16m routed tiles
    down_kernel<<<256 + NEXP * 16 * 16, 256, 0, stream>>>(
        hsh, sdT, act, wdT, sh_out, r_out, counts, bid);

    final_add_kernel<<<(n4 + 255) / 256, 256, 0, stream>>>(sh_out, r_out, out, n4);
}